// Round 5
// baseline (5793.882 us; speedup 1.0000x reference)
//
#include <hip/hip_runtime.h>
#include <hip/hip_cooperative_groups.h>

typedef __bf16 bf16;
typedef short s16x8 __attribute__((ext_vector_type(8)));
typedef float f32x4 __attribute__((ext_vector_type(4)));

#define MFMA16(a, b, c) __builtin_amdgcn_mfma_f32_16x16x32_bf16((a), (b), (c), 0, 0, 0)

__device__ __forceinline__ float sigf(float x) { return 1.0f / (1.0f + expf(-x)); }
__device__ __forceinline__ s16x8 ld8(const bf16* p) { return *(const s16x8*)p; }

// ---------------- device-global workspace (fp32 in / fp32 out: R3-verified) --
__device__ bf16  g_xhi[64 * 64 * 512], g_xlo[64 * 64 * 512];
__device__ bf16  g_wwhi[1024 * 512], g_wwlo[1024 * 512];
__device__ bf16  g_wchi[2560 * 1024], g_wclo[2560 * 1024];
__device__ float g_c[64 * 64 * 512];       // c state fp32
__device__ float g_hf[64 * 64 * 512];      // h state fp32 (for output)
__device__ bf16  g_hhi[64 * 64 * 512];     // h state hi (GEMM operand)
__device__ bf16  g_hlo[64 * 64 * 512];     // h state lo (h = hi+lo)
__device__ float g_candh[64 * 63 * 512];
__device__ float g_candc[64 * 63 * 512];
__device__ float g_spinit[64 * 63 * 32];
__device__ float g_spart[128 * 32];
__device__ int4  g_meta[128];

// ---------------- prep: fp32 -> bf16 hi/lo split ---------------------------
__global__ __launch_bounds__(256) void k_prep_split(const float* __restrict__ src,
                                                    int n, bf16* __restrict__ hi,
                                                    bf16* __restrict__ lo) {
    for (int i = blockIdx.x * 256 + threadIdx.x; i < n; i += gridDim.x * 256) {
        float v = src[i];
        bf16 h = (bf16)v;
        hi[i] = h;
        lo[i] = (bf16)(v - (float)h);
    }
}

// ---------------------------------------------------------------------------
// K0: leaf projection  state = x @ w_word.T + b_word  (M=4096, N=1024, K=512)
// 3-pass hi/lo MFMA. Layouts (m89/m120 verified):
//   A[m=lane&15][k=quad*8+j], B[k=quad*8+j][n=lane&15], D row=quad*4+reg, col=lane&15
// ---------------------------------------------------------------------------
__global__ __launch_bounds__(64) void k_leaf(const float* __restrict__ b_word) {
    int rg = blockIdx.x, cg = blockIdx.y;
    int lane = threadIdx.x, l15 = lane & 15, quad = lane >> 4;
    const bf16* axh = g_xhi + (size_t)(rg * 16 + l15) * 512;
    const bf16* axl = g_xlo + (size_t)(rg * 16 + l15) * 512;
    const bf16* bwh = g_wwhi + (size_t)(cg * 64 + l15) * 512;
    const bf16* bwl = g_wwlo + (size_t)(cg * 64 + l15) * 512;
    f32x4 acc[4] = {};
    for (int kc = 0; kc < 16; ++kc) {
        int k = kc * 32 + quad * 8;
        s16x8 aH = ld8(axh + k), aL = ld8(axl + k);
#pragma unroll
        for (int t = 0; t < 4; ++t) {
            s16x8 bH = ld8(bwh + (size_t)t * 16 * 512 + k);
            s16x8 bL = ld8(bwl + (size_t)t * 16 * 512 + k);
            acc[t] = MFMA16(aH, bH, acc[t]);
            acc[t] = MFMA16(aH, bL, acc[t]);
            acc[t] = MFMA16(aL, bH, acc[t]);
        }
    }
#pragma unroll
    for (int t = 0; t < 4; ++t) {
        int col = cg * 64 + t * 16 + l15;
        float bw = b_word[col];
#pragma unroll
        for (int r = 0; r < 4; ++r) {
            int m = rg * 16 + quad * 4 + r;
            float v = acc[t][r] + bw;
            if (col < 512) {
                bf16 hi = (bf16)v;
                g_hf[(size_t)m * 512 + col] = v;
                g_hhi[(size_t)m * 512 + col] = hi;
                g_hlo[(size_t)m * 512 + col] = (bf16)(v - (float)hi);
            } else {
                g_c[(size_t)m * 512 + (col - 512)] = v;
            }
        }
    }
}

// ---------------------------------------------------------------------------
// K1: initial candidates, all pairs (b,j). 4 row-tiles/wave, gates-outer:
// per K-step 18 loads feed 60 MFMAs (was 12:15) -> latency-hiding by ILP.
// grid (63, 32): 64 rows x 16 cols x 5 gates per wave.
// ---------------------------------------------------------------------------
__global__ __launch_bounds__(64) void k_cells_init(const int* __restrict__ length,
                                                   const float* __restrict__ b_comp,
                                                   const float* __restrict__ q) {
    int rg = blockIdx.x;            // 0..62
    int fg = blockIdx.y;            // 0..31
    int lane = threadIdx.x, l15 = lane & 15, quad = lane >> 4;

    const bf16 *ahi[4], *alo[4];
#pragma unroll
    for (int t = 0; t < 4; ++t) {
        int r = rg * 64 + t * 16 + l15;      // pair row 0..4031
        int b = r / 63, j = r - b * 63;
        ahi[t] = g_hhi + (size_t)(b * 64 + j) * 512;
        alo[t] = g_hlo + (size_t)(b * 64 + j) * 512;
    }
    const bf16* wh = g_wchi + (size_t)(fg * 16 + l15) * 1024;
    const bf16* wl = g_wclo + (size_t)(fg * 16 + l15) * 1024;
    f32x4 acc[4][5] = {};
    for (int kc = 0; kc < 32; ++kc) {
        int k = kc * 32 + quad * 8;
        int kk = k & 511;
        size_t sh = (k < 512) ? 0 : 512;     // row j vs j+1 (contiguous rows)
        s16x8 aH[4], aL[4];
#pragma unroll
        for (int t = 0; t < 4; ++t) {
            aH[t] = ld8(ahi[t] + sh + kk);
            aL[t] = ld8(alo[t] + sh + kk);
        }
#pragma unroll
        for (int g = 0; g < 5; ++g) {
            s16x8 bH = ld8(wh + (size_t)g * 512 * 1024 + k);
            s16x8 bL = ld8(wl + (size_t)g * 512 * 1024 + k);
#pragma unroll
            for (int t = 0; t < 4; ++t) {
                acc[t][g] = MFMA16(aH[t], bH, acc[t][g]);
                acc[t][g] = MFMA16(aH[t], bL, acc[t][g]);
                acc[t][g] = MFMA16(aL[t], bH, acc[t][g]);
            }
        }
    }
    int col = fg * 16 + l15;
    float bc[5];
#pragma unroll
    for (int g = 0; g < 5; ++g) bc[g] = b_comp[g * 512 + col];
    float qv = q[col];
#pragma unroll
    for (int t = 0; t < 4; ++t) {
#pragma unroll
        for (int rr = 0; rr < 4; ++rr) {
            int R = rg * 64 + t * 16 + quad * 4 + rr;
            int B_ = R / 63, J = R - B_ * 63;
            bool act = (J <= length[B_] - 2);
            float gi = acc[t][0][rr] + bc[0];
            float fl = acc[t][1][rr] + bc[1];
            float fr = acc[t][2][rr] + bc[2];
            float gu = acc[t][3][rr] + bc[3];
            float go = acc[t][4][rr] + bc[4];
            float cl = g_c[(size_t)(B_ * 64 + J) * 512 + col];
            float cr = g_c[(size_t)(B_ * 64 + J + 1) * 512 + col];
            float cn = cl * sigf(fl + 1.0f) + cr * sigf(fr + 1.0f) + tanhf(gu) * sigf(gi);
            float hn = sigf(go) * tanhf(cn);
            float sp = hn * qv;
#pragma unroll
            for (int off = 1; off < 16; off <<= 1) sp += __shfl_xor(sp, off, 16);
            if (act) {
                g_candh[(size_t)(B_ * 63 + J) * 512 + col] = hn;
                g_candc[(size_t)(B_ * 63 + J) * 512 + col] = cn;
                if (l15 == 0) g_spinit[(size_t)R * 32 + fg] = sp;
            }
        }
    }
}

// ---------------------------------------------------------------------------
// K_loop: cooperative 63-iteration merge loop + output. 256 blocks x 64 thr.
// Blocks 0..63: per-batch list state persistent in LDS; sel + commit + meta.
// All blocks: per-iter GEMM for the <=2 new pairs/batch (8 rg x 32 fg).
// ---------------------------------------------------------------------------
__global__ __launch_bounds__(64) void k_loop(const int* __restrict__ length,
                                             const float* __restrict__ b_comp,
                                             const float* __restrict__ q,
                                             float* __restrict__ out) {
    namespace cg = cooperative_groups;
    cg::grid_group grid = cg::this_grid();
    int blk = blockIdx.x, lane = threadIdx.x;
    int l15 = lane & 15, quad = lane >> 4;

    __shared__ int s_next[64], s_prev[64], s_aliv[64];
    __shared__ float s_score[64];
    __shared__ int s_sel, s_np[2];
    __shared__ int4 s_desc[16];
    const float sqrt_h = 22.627416997969522f;

    bool isbatch = (blk < 64);
    int b = blk, len = 0;
    if (isbatch) {
        len = length[b];
        s_next[lane] = (lane < len - 1) ? (lane + 1) : -1;
        s_prev[lane] = (lane > 0 && lane < len) ? (lane - 1) : -1;
        s_aliv[lane] = (lane < len) ? 1 : 0;
        float sc = -3.0e38f;
        if (lane <= len - 2) {
            float s = 0.0f;
            for (int f = 0; f < 32; ++f) s += g_spinit[(size_t)(b * 63 + lane) * 32 + f];
            sc = s / sqrt_h;
        }
        s_score[lane] = sc;
        if (lane == 0) { s_np[0] = -1; s_np[1] = -1; }
        __syncthreads();
    }

    int rg = blk >> 5, fg = blk & 31;
    int col = fg * 16 + l15;
    float bc[5];
#pragma unroll
    for (int g = 0; g < 5; ++g) bc[g] = b_comp[g * 512 + col];
    float qv = q[col];
    const bf16* wh = g_wchi + (size_t)col * 1024;
    const bf16* wl = g_wclo + (size_t)col * 1024;

    for (int it = 0; it < 63; ++it) {
        // ------------- phase A: selection + commit (batch blocks) ----------
        if (isbatch) {
            bool active = (it <= len - 2);
            if (active) {
                if (it > 0) {   // fold scores of pairs refreshed last iteration
                    int s = lane >> 5, f = lane & 31;
                    int p = s_np[s];
                    float v = (p >= 0) ? g_spart[(size_t)(2 * b + s) * 32 + f] : 0.0f;
#pragma unroll
                    for (int off = 1; off < 32; off <<= 1) v += __shfl_xor(v, off, 32);
                    if (f == 0 && p >= 0) s_score[p] = v / sqrt_h;
                    __syncthreads();
                }
                // argmax, first-index tie-break
                float val = -3.0e38f;
                int idx = lane;
                if (lane < 63 && s_aliv[lane] && s_next[lane] >= 0) val = s_score[lane];
#pragma unroll
                for (int off = 1; off < 64; off <<= 1) {
                    float ov = __shfl_xor(val, off, 64);
                    int oi = __shfl_xor(idx, off, 64);
                    if (ov > val || (ov == val && oi < idx)) { val = ov; idx = oi; }
                }
                if (lane == 0) s_sel = idx;
                __syncthreads();
                int a = s_sel;
                if (a < 0) a = 0;
                if (a > 62) a = 62;
                const float* ch = g_candh + (size_t)(b * 63 + a) * 512;
                const float* cc = g_candc + (size_t)(b * 63 + a) * 512;
                float* cs = g_c + (size_t)(b * 64 + a) * 512;
                float* hf = g_hf + (size_t)(b * 64 + a) * 512;
                bf16* hh = g_hhi + (size_t)(b * 64 + a) * 512;
                bf16* hl = g_hlo + (size_t)(b * 64 + a) * 512;
                for (int d = lane; d < 512; d += 64) {
                    float hv = ch[d];
                    cs[d] = cc[d];
                    hf[d] = hv;
                    bf16 hi = (bf16)hv;
                    hh[d] = hi;
                    hl[d] = (bf16)(hv - (float)hi);
                }
                if (lane == 0) {
                    int bn = s_next[a];
                    int nn = (bn >= 0) ? s_next[bn] : -1;
                    s_next[a] = nn;
                    if (nn >= 0) s_prev[nn] = a;
                    if (bn >= 0) s_aliv[bn] = 0;
                    int pL = s_prev[a];
                    int pR = (nn >= 0) ? a : -1;
                    s_np[0] = pL;
                    s_np[1] = pR;
                    g_meta[2 * b] = (pL >= 0) ? make_int4(b, pL, a, pL) : make_int4(b, 0, 1, -1);
                    g_meta[2 * b + 1] = (pR >= 0) ? make_int4(b, a, nn, a) : make_int4(b, 0, 1, -1);
                }
                __syncthreads();
            } else if (lane == 0) {
                g_meta[2 * b] = make_int4(b, 0, 1, -1);
                g_meta[2 * b + 1] = make_int4(b, 0, 1, -1);
            }
        }
        grid.sync();
        // ------------- phase B: cell GEMM for the new pairs ---------------
        if (it < 62) {
            if (lane < 16) s_desc[lane] = g_meta[rg * 16 + lane];
            __syncthreads();
            int4 dme = s_desc[l15];
            const bf16* ahiL = g_hhi + (size_t)(dme.x * 64 + dme.y) * 512;
            const bf16* aloL = g_hlo + (size_t)(dme.x * 64 + dme.y) * 512;
            const bf16* ahiR = g_hhi + (size_t)(dme.x * 64 + dme.z) * 512;
            const bf16* aloR = g_hlo + (size_t)(dme.x * 64 + dme.z) * 512;
            f32x4 acc[5] = {};
            for (int kc = 0; kc < 32; ++kc) {
                int k = kc * 32 + quad * 8;
                int kk = k & 511;
                const bf16* ah = (k < 512) ? ahiL : ahiR;
                const bf16* al = (k < 512) ? aloL : aloR;
                s16x8 aH = ld8(ah + kk);
                s16x8 aL = ld8(al + kk);
#pragma unroll
                for (int g = 0; g < 5; ++g) {
                    s16x8 bH = ld8(wh + (size_t)g * 512 * 1024 + k);
                    s16x8 bL = ld8(wl + (size_t)g * 512 * 1024 + k);
                    acc[g] = MFMA16(aH, bH, acc[g]);
                    acc[g] = MFMA16(aH, bL, acc[g]);
                    acc[g] = MFMA16(aL, bH, acc[g]);
                }
            }
#pragma unroll
            for (int rr = 0; rr < 4; ++rr) {
                int rowm = quad * 4 + rr;
                int4 D = s_desc[rowm];
                float gi = acc[0][rr] + bc[0];
                float fl = acc[1][rr] + bc[1];
                float fr = acc[2][rr] + bc[2];
                float gu = acc[3][rr] + bc[3];
                float go = acc[4][rr] + bc[4];
                float cl = g_c[(size_t)(D.x * 64 + D.y) * 512 + col];
                float cr = g_c[(size_t)(D.x * 64 + D.z) * 512 + col];
                float cn = cl * sigf(fl + 1.0f) + cr * sigf(fr + 1.0f) + tanhf(gu) * sigf(gi);
                float hn = sigf(go) * tanhf(cn);
                float sp = hn * qv;
#pragma unroll
                for (int off = 1; off < 16; off <<= 1) sp += __shfl_xor(sp, off, 16);
                if (D.w >= 0) {
                    g_candh[(size_t)(D.x * 63 + D.w) * 512 + col] = hn;
                    g_candc[(size_t)(D.x * 63 + D.w) * 512 + col] = cn;
                    if (l15 == 0) g_spart[(size_t)(rg * 16 + rowm) * 32 + fg] = sp;
                }
            }
            __syncthreads();
            grid.sync();
        }
    }
    // ------------- output: root is always slot 0 ---------------------------
    if (isbatch) {
        for (int d = lane; d < 512; d += 64) {
            out[(size_t)b * 512 + d] = g_hf[(size_t)(b * 64) * 512 + d];
            out[(size_t)(64 * 512) + b * 512 + d] = g_c[(size_t)(b * 64) * 512 + d];
        }
    }
}

// ---------------------------------------------------------------------------
extern "C" void kernel_launch(void* const* d_in, const int* in_sizes, int n_in,
                              void* d_out, int out_size, void* d_ws, size_t ws_size,
                              hipStream_t stream) {
    const float* x = (const float*)d_in[0];
    const int* length = (const int*)d_in[1];
    const float* w_word = (const float*)d_in[2];
    const float* b_word = (const float*)d_in[3];
    const float* w_comp = (const float*)d_in[4];
    const float* b_comp = (const float*)d_in[5];
    const float* q = (const float*)d_in[6];
    float* out = (float*)d_out;

    bf16 *xhi, *xlo, *wwhi, *wwlo, *wchi, *wclo;
    hipGetSymbolAddress((void**)&xhi, HIP_SYMBOL(g_xhi));
    hipGetSymbolAddress((void**)&xlo, HIP_SYMBOL(g_xlo));
    hipGetSymbolAddress((void**)&wwhi, HIP_SYMBOL(g_wwhi));
    hipGetSymbolAddress((void**)&wwlo, HIP_SYMBOL(g_wwlo));
    hipGetSymbolAddress((void**)&wchi, HIP_SYMBOL(g_wchi));
    hipGetSymbolAddress((void**)&wclo, HIP_SYMBOL(g_wclo));

    hipLaunchKernelGGL(k_prep_split, dim3(1024), dim3(256), 0, stream,
                       x, 64 * 64 * 512, xhi, xlo);
    hipLaunchKernelGGL(k_prep_split, dim3(256), dim3(256), 0, stream,
                       w_word, 1024 * 512, wwhi, wwlo);
    hipLaunchKernelGGL(k_prep_split, dim3(1024), dim3(256), 0, stream,
                       w_comp, 2560 * 1024, wchi, wclo);

    hipLaunchKernelGGL(k_leaf, dim3(256, 16), dim3(64), 0, stream, b_word);
    hipLaunchKernelGGL(k_cells_init, dim3(63, 32), dim3(64), 0, stream,
                       length, b_comp, q);

    void* args[] = {(void*)&length, (void*)&b_comp, (void*)&q, (void*)&out};
    hipLaunchCooperativeKernel((void*)k_loop, dim3(256), dim3(64), args, 0, stream);
}

// Round 6
// 3238.601 us; speedup vs baseline: 1.7890x; 1.7890x over previous
//
#include <hip/hip_runtime.h>

typedef __bf16 bf16;
typedef short s16x8 __attribute__((ext_vector_type(8)));
typedef float f32x4 __attribute__((ext_vector_type(4)));

#define MFMA16(a, b, c) __builtin_amdgcn_mfma_f32_16x16x32_bf16((a), (b), (c), 0, 0, 0)

__device__ __forceinline__ float sigf(float x) { return 1.0f / (1.0f + expf(-x)); }
__device__ __forceinline__ s16x8 ld8(const bf16* p) { return *(const s16x8*)p; }

// ---------------- device-global workspace (fp32 in / fp32 out: R3-verified) --
__device__ bf16  g_xhi[64 * 64 * 512], g_xlo[64 * 64 * 512];
__device__ bf16  g_wwhi[1024 * 512], g_wwlo[1024 * 512];
__device__ bf16  g_wchi[2560 * 1024], g_wclo[2560 * 1024];
__device__ float g_c[64 * 64 * 512];       // c state fp32
__device__ float g_hf[64 * 64 * 512];      // h state fp32 (for output)
__device__ bf16  g_hhi[64 * 64 * 512];     // h state hi (GEMM operand)
__device__ bf16  g_hlo[64 * 64 * 512];     // h state lo (h = hi+lo)
__device__ float g_candh[64 * 63 * 512];
__device__ float g_candc[64 * 63 * 512];
__device__ float g_spinit[64 * 63 * 32];
__device__ float g_spart[128 * 32];
__device__ int4  g_meta[128];
__device__ int   g_next[64 * 64], g_prev[64 * 64], g_aliv[64 * 64];
__device__ float g_score[64 * 64];
__device__ int   g_np[128];

// ---------------- prep: fp32 -> bf16 hi/lo split ---------------------------
__global__ __launch_bounds__(256) void k_prep_split(const float* __restrict__ src,
                                                    int n, bf16* __restrict__ hi,
                                                    bf16* __restrict__ lo) {
    for (int i = blockIdx.x * 256 + threadIdx.x; i < n; i += gridDim.x * 256) {
        float v = src[i];
        bf16 h = (bf16)v;
        hi[i] = h;
        lo[i] = (bf16)(v - (float)h);
    }
}

// ---------------------------------------------------------------------------
// K0: leaf projection. grid (16 cg, 256 rg): cg-major => cg -> fixed XCD,
// w_word slice stays L2-resident per XCD.
// MFMA layouts (m89/m120): A[m=l15][k=quad*8+j], B[k][n=l15], D row=quad*4+r.
// ---------------------------------------------------------------------------
__global__ __launch_bounds__(64) void k_leaf(const float* __restrict__ b_word) {
    int cg = blockIdx.x, rg = blockIdx.y;
    int lane = threadIdx.x, l15 = lane & 15, quad = lane >> 4;
    const bf16* axh = g_xhi + (size_t)(rg * 16 + l15) * 512;
    const bf16* axl = g_xlo + (size_t)(rg * 16 + l15) * 512;
    const bf16* bwh = g_wwhi + (size_t)(cg * 64 + l15) * 512;
    const bf16* bwl = g_wwlo + (size_t)(cg * 64 + l15) * 512;
    f32x4 acc[4] = {};
    for (int kc = 0; kc < 16; ++kc) {
        int k = kc * 32 + quad * 8;
        s16x8 aH = ld8(axh + k), aL = ld8(axl + k);
#pragma unroll
        for (int t = 0; t < 4; ++t) {
            s16x8 bH = ld8(bwh + (size_t)t * 16 * 512 + k);
            s16x8 bL = ld8(bwl + (size_t)t * 16 * 512 + k);
            acc[t] = MFMA16(aH, bH, acc[t]);
            acc[t] = MFMA16(aH, bL, acc[t]);
            acc[t] = MFMA16(aL, bH, acc[t]);
        }
    }
#pragma unroll
    for (int t = 0; t < 4; ++t) {
        int col = cg * 64 + t * 16 + l15;
        float bw = b_word[col];
#pragma unroll
        for (int r = 0; r < 4; ++r) {
            int m = rg * 16 + quad * 4 + r;
            float v = acc[t][r] + bw;
            if (col < 512) {
                bf16 hi = (bf16)v;
                g_hf[(size_t)m * 512 + col] = v;
                g_hhi[(size_t)m * 512 + col] = hi;
                g_hlo[(size_t)m * 512 + col] = (bf16)(v - (float)hi);
            } else {
                g_c[(size_t)m * 512 + (col - 512)] = v;
            }
        }
    }
}

// ---------------------------------------------------------------------------
// K1: initial candidates. grid (32 fg, 63 rg): fg-major => fg -> fixed XCD,
// each block's 320KB w_comp slice L2-warm. 4 row-tiles/wave, gates-outer.
// ---------------------------------------------------------------------------
__global__ __launch_bounds__(64) void k_cells_init(const int* __restrict__ length,
                                                   const float* __restrict__ b_comp,
                                                   const float* __restrict__ q) {
    int fg = blockIdx.x;            // 0..31
    int rg = blockIdx.y;            // 0..62
    int lane = threadIdx.x, l15 = lane & 15, quad = lane >> 4;

    const bf16 *ahi[4], *alo[4];
#pragma unroll
    for (int t = 0; t < 4; ++t) {
        int r = rg * 64 + t * 16 + l15;      // pair row 0..4031
        int b = r / 63, j = r - b * 63;
        ahi[t] = g_hhi + (size_t)(b * 64 + j) * 512;
        alo[t] = g_hlo + (size_t)(b * 64 + j) * 512;
    }
    const bf16* wh = g_wchi + (size_t)(fg * 16 + l15) * 1024;
    const bf16* wl = g_wclo + (size_t)(fg * 16 + l15) * 1024;
    f32x4 acc[4][5] = {};
    for (int kc = 0; kc < 32; ++kc) {
        int k = kc * 32 + quad * 8;
        int kk = k & 511;
        size_t sh = (k < 512) ? 0 : 512;     // row j vs j+1 (contiguous rows)
        s16x8 aH[4], aL[4];
#pragma unroll
        for (int t = 0; t < 4; ++t) {
            aH[t] = ld8(ahi[t] + sh + kk);
            aL[t] = ld8(alo[t] + sh + kk);
        }
#pragma unroll
        for (int g = 0; g < 5; ++g) {
            s16x8 bH = ld8(wh + (size_t)g * 512 * 1024 + k);
            s16x8 bL = ld8(wl + (size_t)g * 512 * 1024 + k);
#pragma unroll
            for (int t = 0; t < 4; ++t) {
                acc[t][g] = MFMA16(aH[t], bH, acc[t][g]);
                acc[t][g] = MFMA16(aH[t], bL, acc[t][g]);
                acc[t][g] = MFMA16(aL[t], bH, acc[t][g]);
            }
        }
    }
    int col = fg * 16 + l15;
    float bc[5];
#pragma unroll
    for (int g = 0; g < 5; ++g) bc[g] = b_comp[g * 512 + col];
    float qv = q[col];
#pragma unroll
    for (int t = 0; t < 4; ++t) {
#pragma unroll
        for (int rr = 0; rr < 4; ++rr) {
            int R = rg * 64 + t * 16 + quad * 4 + rr;
            int B_ = R / 63, J = R - B_ * 63;
            bool act = (J <= length[B_] - 2);
            float gi = acc[t][0][rr] + bc[0];
            float fl = acc[t][1][rr] + bc[1];
            float fr = acc[t][2][rr] + bc[2];
            float gu = acc[t][3][rr] + bc[3];
            float go = acc[t][4][rr] + bc[4];
            float cl = g_c[(size_t)(B_ * 64 + J) * 512 + col];
            float cr = g_c[(size_t)(B_ * 64 + J + 1) * 512 + col];
            float cn = cl * sigf(fl + 1.0f) + cr * sigf(fr + 1.0f) + tanhf(gu) * sigf(gi);
            float hn = sigf(go) * tanhf(cn);
            float sp = hn * qv;
#pragma unroll
            for (int off = 1; off < 16; off <<= 1) sp += __shfl_xor(sp, off, 16);
            if (act) {
                g_candh[(size_t)(B_ * 63 + J) * 512 + col] = hn;
                g_candc[(size_t)(B_ * 63 + J) * 512 + col] = cn;
                if (l15 == 0) g_spinit[(size_t)R * 32 + fg] = sp;
            }
        }
    }
}

// ---------------------------------------------------------------------------
// K_sel: per-batch selection + merge commit + list update. 64 blocks x 64 thr.
// ---------------------------------------------------------------------------
__global__ __launch_bounds__(64) void k_sel(const int* __restrict__ length, int it) {
    int b = blockIdx.x, lane = threadIdx.x;
    __shared__ int s_next[64], s_prev[64], s_aliv[64];
    __shared__ float s_score[64];
    __shared__ int s_sel;
    const float sqrt_h = 22.627416997969522f;

    int len = length[b];
    bool active = (it <= len - 2);
    if (!active) {
        if (lane == 0) {
            g_meta[2 * b] = make_int4(b, 0, 1, -1);
            g_meta[2 * b + 1] = make_int4(b, 0, 1, -1);
        }
        return;
    }
    if (it == 0) {
        s_next[lane] = (lane < len - 1) ? (lane + 1) : -1;
        s_prev[lane] = (lane > 0 && lane < len) ? (lane - 1) : -1;
        s_aliv[lane] = (lane < len) ? 1 : 0;
        float sc = -3.0e38f;
        if (lane <= len - 2) {
            float s = 0.0f;
            for (int f = 0; f < 32; ++f) s += g_spinit[(size_t)(b * 63 + lane) * 32 + f];
            sc = s / sqrt_h;
        }
        s_score[lane] = sc;
    } else {
        s_next[lane] = g_next[b * 64 + lane];
        s_prev[lane] = g_prev[b * 64 + lane];
        s_aliv[lane] = g_aliv[b * 64 + lane];
        s_score[lane] = g_score[b * 64 + lane];
        __syncthreads();
        int s = lane >> 5, f = lane & 31;
        int p = g_np[2 * b + s];
        float v = (p >= 0) ? g_spart[(size_t)(2 * b + s) * 32 + f] : 0.0f;
#pragma unroll
        for (int off = 1; off < 32; off <<= 1) v += __shfl_xor(v, off, 32);
        if (f == 0 && p >= 0) s_score[p] = v / sqrt_h;
    }
    __syncthreads();
    // argmax, first-index tie-break (list order is monotone in node id)
    float val = -3.0e38f;
    int idx = lane;
    if (lane < 63 && s_aliv[lane] && s_next[lane] >= 0) val = s_score[lane];
#pragma unroll
    for (int off = 1; off < 64; off <<= 1) {
        float ov = __shfl_xor(val, off, 64);
        int oi = __shfl_xor(idx, off, 64);
        if (ov > val || (ov == val && oi < idx)) { val = ov; idx = oi; }
    }
    if (lane == 0) s_sel = idx;
    __syncthreads();
    int a = s_sel;
    if (a < 0) a = 0;
    if (a > 62) a = 62;
    const float* ch = g_candh + (size_t)(b * 63 + a) * 512;
    const float* cc = g_candc + (size_t)(b * 63 + a) * 512;
    float* cs = g_c + (size_t)(b * 64 + a) * 512;
    float* hf = g_hf + (size_t)(b * 64 + a) * 512;
    bf16* hh = g_hhi + (size_t)(b * 64 + a) * 512;
    bf16* hl = g_hlo + (size_t)(b * 64 + a) * 512;
    for (int d = lane; d < 512; d += 64) {
        float hv = ch[d];
        cs[d] = cc[d];
        hf[d] = hv;
        bf16 hi = (bf16)hv;
        hh[d] = hi;
        hl[d] = (bf16)(hv - (float)hi);
    }
    if (lane == 0) {
        int bn = s_next[a];
        int nn = (bn >= 0) ? s_next[bn] : -1;
        s_next[a] = nn;
        if (nn >= 0) s_prev[nn] = a;
        if (bn >= 0) s_aliv[bn] = 0;
        int pL = s_prev[a];
        int pR = (nn >= 0) ? a : -1;
        g_np[2 * b] = pL;
        g_np[2 * b + 1] = pR;
        g_meta[2 * b] = (pL >= 0) ? make_int4(b, pL, a, pL) : make_int4(b, 0, 1, -1);
        g_meta[2 * b + 1] = (pR >= 0) ? make_int4(b, a, nn, a) : make_int4(b, 0, 1, -1);
    }
    __syncthreads();
    g_next[b * 64 + lane] = s_next[lane];
    g_prev[b * 64 + lane] = s_prev[lane];
    g_aliv[b * 64 + lane] = s_aliv[lane];
    g_score[b * 64 + lane] = s_score[lane];
}

// ---------------------------------------------------------------------------
// K_cell: refresh candidates for the <=2 new pairs/batch.
// grid (32 fg, 4 rg) x 64 thr: fg-major => fg -> fixed XCD (id%8 == fg%8),
// 320KB B-slice per block stays L2-warm across all 62 launches.
// Each block: 2 m-tiles (32 of the 128 meta rows) x 16 cols x 5 gates,
// B cached in registers across the 2 m-tiles: 14 loads : 30 MFMA per K-step.
// ---------------------------------------------------------------------------
__global__ __launch_bounds__(64) void k_cell(const float* __restrict__ b_comp,
                                             const float* __restrict__ q) {
    int fg = blockIdx.x;            // 0..31
    int rg = blockIdx.y;            // 0..3
    int lane = threadIdx.x, l15 = lane & 15, quad = lane >> 4;
    __shared__ int4 s_desc[32];
    if (lane < 32) s_desc[lane] = g_meta[rg * 32 + lane];
    __syncthreads();

    int col = fg * 16 + l15;
    const bf16 *ahiL[2], *aloL[2], *ahiR[2], *aloR[2];
#pragma unroll
    for (int t = 0; t < 2; ++t) {
        int4 d = s_desc[t * 16 + l15];
        ahiL[t] = g_hhi + (size_t)(d.x * 64 + d.y) * 512;
        aloL[t] = g_hlo + (size_t)(d.x * 64 + d.y) * 512;
        ahiR[t] = g_hhi + (size_t)(d.x * 64 + d.z) * 512;
        aloR[t] = g_hlo + (size_t)(d.x * 64 + d.z) * 512;
    }
    const bf16* wh = g_wchi + (size_t)col * 1024;
    const bf16* wl = g_wclo + (size_t)col * 1024;
    f32x4 acc[2][5] = {};
    for (int kc = 0; kc < 32; ++kc) {
        int k = kc * 32 + quad * 8;
        int kk = k & 511;
        bool left = (k < 512);
        s16x8 bH[5], bL[5];
#pragma unroll
        for (int g = 0; g < 5; ++g) {
            bH[g] = ld8(wh + (size_t)g * 512 * 1024 + k);
            bL[g] = ld8(wl + (size_t)g * 512 * 1024 + k);
        }
#pragma unroll
        for (int t = 0; t < 2; ++t) {
            s16x8 aH = ld8((left ? ahiL[t] : ahiR[t]) + kk);
            s16x8 aL = ld8((left ? aloL[t] : aloR[t]) + kk);
#pragma unroll
            for (int g = 0; g < 5; ++g) {
                acc[t][g] = MFMA16(aH, bH[g], acc[t][g]);
                acc[t][g] = MFMA16(aH, bL[g], acc[t][g]);
                acc[t][g] = MFMA16(aL, bH[g], acc[t][g]);
            }
        }
    }
    float bc[5];
#pragma unroll
    for (int g = 0; g < 5; ++g) bc[g] = b_comp[g * 512 + col];
    float qv = q[col];
#pragma unroll
    for (int t = 0; t < 2; ++t) {
#pragma unroll
        for (int rr = 0; rr < 4; ++rr) {
            int rowm = t * 16 + quad * 4 + rr;
            int4 D = s_desc[rowm];
            float gi = acc[t][0][rr] + bc[0];
            float fl = acc[t][1][rr] + bc[1];
            float fr = acc[t][2][rr] + bc[2];
            float gu = acc[t][3][rr] + bc[3];
            float go = acc[t][4][rr] + bc[4];
            float cl = g_c[(size_t)(D.x * 64 + D.y) * 512 + col];
            float cr = g_c[(size_t)(D.x * 64 + D.z) * 512 + col];
            float cn = cl * sigf(fl + 1.0f) + cr * sigf(fr + 1.0f) + tanhf(gu) * sigf(gi);
            float hn = sigf(go) * tanhf(cn);
            float sp = hn * qv;
#pragma unroll
            for (int off = 1; off < 16; off <<= 1) sp += __shfl_xor(sp, off, 16);
            if (D.w >= 0) {
                g_candh[(size_t)(D.x * 63 + D.w) * 512 + col] = hn;
                g_candc[(size_t)(D.x * 63 + D.w) * 512 + col] = cn;
                if (l15 == 0) g_spart[(size_t)(rg * 32 + rowm) * 32 + fg] = sp;
            }
        }
    }
}

// ---------------------------------------------------------------------------
__global__ __launch_bounds__(64) void k_out(float* __restrict__ out) {
    int b = blockIdx.x, lane = threadIdx.x;
    for (int d = lane; d < 512; d += 64) {
        out[(size_t)b * 512 + d] = g_hf[(size_t)(b * 64) * 512 + d];
        out[(size_t)(64 * 512) + b * 512 + d] = g_c[(size_t)(b * 64) * 512 + d];
    }
}

// ---------------------------------------------------------------------------
extern "C" void kernel_launch(void* const* d_in, const int* in_sizes, int n_in,
                              void* d_out, int out_size, void* d_ws, size_t ws_size,
                              hipStream_t stream) {
    const float* x = (const float*)d_in[0];
    const int* length = (const int*)d_in[1];
    const float* w_word = (const float*)d_in[2];
    const float* b_word = (const float*)d_in[3];
    const float* w_comp = (const float*)d_in[4];
    const float* b_comp = (const float*)d_in[5];
    const float* q = (const float*)d_in[6];
    float* out = (float*)d_out;

    bf16 *xhi, *xlo, *wwhi, *wwlo, *wchi, *wclo;
    hipGetSymbolAddress((void**)&xhi, HIP_SYMBOL(g_xhi));
    hipGetSymbolAddress((void**)&xlo, HIP_SYMBOL(g_xlo));
    hipGetSymbolAddress((void**)&wwhi, HIP_SYMBOL(g_wwhi));
    hipGetSymbolAddress((void**)&wwlo, HIP_SYMBOL(g_wwlo));
    hipGetSymbolAddress((void**)&wchi, HIP_SYMBOL(g_wchi));
    hipGetSymbolAddress((void**)&wclo, HIP_SYMBOL(g_wclo));

    hipLaunchKernelGGL(k_prep_split, dim3(1024), dim3(256), 0, stream,
                       x, 64 * 64 * 512, xhi, xlo);
    hipLaunchKernelGGL(k_prep_split, dim3(256), dim3(256), 0, stream,
                       w_word, 1024 * 512, wwhi, wwlo);
    hipLaunchKernelGGL(k_prep_split, dim3(1024), dim3(256), 0, stream,
                       w_comp, 2560 * 1024, wchi, wclo);

    hipLaunchKernelGGL(k_leaf, dim3(16, 256), dim3(64), 0, stream, b_word);
    hipLaunchKernelGGL(k_cells_init, dim3(32, 63), dim3(64), 0, stream,
                       length, b_comp, q);
    for (int it = 0; it < 63; ++it) {
        hipLaunchKernelGGL(k_sel, dim3(64), dim3(64), 0, stream, length, it);
        if (it < 62)
            hipLaunchKernelGGL(k_cell, dim3(32, 4), dim3(64), 0, stream, b_comp, q);
    }
    hipLaunchKernelGGL(k_out, dim3(64), dim3(64), 0, stream, out);
}